// Round 5
// baseline (683.103 us; speedup 1.0000x reference)
//
#include <hip/hip_runtime.h>
#include <cstdint>

#define N_NODES 100000
#define N_EDGES 1600000
#define SCAN_NB 391            // ceil(N/256)
#define YD 12                  // [hw0..7, p1, p2, dinv1, dinv1^2]
#define SC_RANGE 12500
#define GEMM_NB 3125           // 3125 blocks x 4 waves x 8 rows = 100000
#define CHUNKS 1563            // ceil(E/1024)
#define SCAT_NB (CHUNKS * 8)

// ---------------- count: XCD-private histograms (copy = blockIdx&7) ----------------
__global__ void k_count(const int* __restrict__ col, int* __restrict__ cnt8) {
  int cb = blockIdx.x;
  int base = (cb & 7) * N_NODES;
  int e0 = (cb * 256 + threadIdx.x) * 4;
  if (e0 >= N_EDGES) return;
  int4 c = *(const int4*)(col + e0);
  atomicAdd(&cnt8[base + c.x], 1); atomicAdd(&cnt8[base + c.y], 1);
  atomicAdd(&cnt8[base + c.z], 1); atomicAdd(&cnt8[base + c.w], 1);
}

// ---------------- scans ----------------
// scan1: sum the 8 histogram copies -> total into cnt8[0:N], block-exclusive scan
__global__ __launch_bounds__(256) void k_scan1(int* __restrict__ cnt8,
                                               int* __restrict__ off,
                                               int* __restrict__ bsum) {
  __shared__ int s[256];
  int t = threadIdx.x;
  int i = blockIdx.x * 256 + t;
  int v = 0;
  if (i < N_NODES) {
#pragma unroll
    for (int c = 0; c < 8; ++c) v += cnt8[c * N_NODES + i];
    cnt8[i] = v;  // copy0 becomes total
  }
  s[t] = v;
  __syncthreads();
  for (int d = 1; d < 256; d <<= 1) {
    int a = (t >= d) ? s[t - d] : 0;
    __syncthreads();
    s[t] += a;
    __syncthreads();
  }
  if (i < N_NODES) off[i] = s[t] - v;
  if (t == 255) bsum[blockIdx.x] = s[255];
}

__global__ __launch_bounds__(512) void k_scan2(const int* __restrict__ bsum,
                                               int* __restrict__ bpre) {
  __shared__ int s[512];
  int t = threadIdx.x;
  int v = (t < SCAN_NB) ? bsum[t] : 0;
  s[t] = v;
  __syncthreads();
  for (int d = 1; d < 512; d <<= 1) {
    int a = (t >= d) ? s[t - d] : 0;
    __syncthreads();
    s[t] += a;
    __syncthreads();
  }
  if (t < SCAN_NB) bpre[t] = s[t] - v;
}

// scan3: finalize offsets+cursors, pack dinv1 and dinv1^2 into y[i][10:12]
__global__ void k_scan3(const int* __restrict__ cnt_tot, const int* __restrict__ bpre,
                        int* __restrict__ off, int* __restrict__ cursor,
                        float* __restrict__ y) {
  int i = blockIdx.x * 256 + threadIdx.x;
  if (i >= N_NODES) return;
  int o = off[i] + bpre[i >> 8];
  off[i] = o;
  cursor[i] = o;
  float di = rsqrtf((float)cnt_tot[i] + 1.0f);
  *(float2*)(y + (size_t)i * YD + 10) = make_float2(di, di * di);
  if (i == 0) off[N_NODES] = N_EDGES;
}

// ---------------- phase E: gemm blocks + scatter blocks + kc block ----------------
__global__ __launch_bounds__(256) void k_phaseE(
    const float* __restrict__ x, const float* __restrict__ W0,
    const float* __restrict__ W1, const float* __restrict__ Wnb,
    const float* __restrict__ Wself, const float* __restrict__ Watt,
    const float* __restrict__ b0, const float* __restrict__ bnb,
    const float* __restrict__ bself, const float* __restrict__ batt,
    const int* __restrict__ row, const int* __restrict__ col,
    int* __restrict__ cursor, int* __restrict__ ssrc,
    float* __restrict__ y, float* __restrict__ kc) {
  __shared__ float M[32][10];
  __shared__ float wl[5120];  // [j][k] transposed folded weight, 20 KB
  const int t = threadIdx.x;

  if (blockIdx.x < GEMM_NB) {
    // build M = [W1 | Wnb@Watt[:8] | Wself@Watt[8:]] then wl = (W0@M)^T
    if (t < 32) {
      for (int j = 0; j < 8; ++j) M[t][j] = W1[t * 8 + j];
      float a1 = 0.f, a2 = 0.f;
      for (int j = 0; j < 8; ++j) {
        a1 += Wnb[t * 8 + j] * Watt[j];
        a2 += Wself[t * 8 + j] * Watt[8 + j];
      }
      M[t][8] = a1; M[t][9] = a2;
    }
    __syncthreads();
    for (int o = t; o < 5120; o += 256) {
      int j = o >> 9, k = o & 511;
      float a = 0.f;
#pragma unroll
      for (int m = 0; m < 32; ++m) a += W0[k * 32 + m] * M[m][j];
      wl[j * 512 + k] = a;
    }
    __syncthreads();
    // 8 rows per wave, 3-stage 8-lane reduce
    const int lane = t & 63;
    const int wave = (blockIdx.x << 2) + (t >> 6);
    const int p = lane & 7;
    const int nrow = wave * 8 + (lane >> 3);
    const float* xr = x + (size_t)nrow * 512;
    float acc[10];
#pragma unroll
    for (int j = 0; j < 10; ++j) acc[j] = 0.f;
#pragma unroll 4
    for (int it = 0; it < 16; ++it) {
      const int k0 = it * 32 + p * 4;
      float4 xv = *(const float4*)(xr + k0);
#pragma unroll
      for (int j = 0; j < 10; ++j) {
        float4 wv = *(const float4*)&wl[j * 512 + k0];
        acc[j] += xv.x * wv.x + xv.y * wv.y + xv.z * wv.z + xv.w * wv.w;
      }
    }
#pragma unroll
    for (int d = 1; d < 8; d <<= 1)
#pragma unroll
      for (int j = 0; j < 10; ++j) acc[j] += __shfl_xor(acc[j], d, 64);
    float* yp = y + (size_t)nrow * YD;
    if (p == 0) {
      *(float4*)yp       = make_float4(acc[0], acc[1], acc[2], acc[3]);
      *(float4*)(yp + 4) = make_float4(acc[4], acc[5], acc[6], acc[7]);
    } else if (p == 1) {
      *(float2*)(yp + 8) = make_float2(acc[8], acc[9]);  // [10:12] owned by scan3
    }
  } else if (blockIdx.x < GEMM_NB + SCAT_NB) {
    // XCD-localized scatter
    int sb = blockIdx.x - GEMM_NB;
    int range = sb & 7;
    int chunk = sb >> 3;
    int e0 = (chunk * 256 + t) * 4;
    if (e0 >= N_EDGES) return;
    int lo = range * SC_RANGE, hi = lo + SC_RANGE;
    int4 c4 = *(const int4*)(col + e0);
    int4 r4 = *(const int4*)(row + e0);
    int cs[4] = {c4.x, c4.y, c4.z, c4.w};
    int rs[4] = {r4.x, r4.y, r4.z, r4.w};
#pragma unroll
    for (int k = 0; k < 4; ++k) {
      int c = cs[k];
      if (c >= lo && c < hi) {
        int pp = atomicAdd(&cursor[c], 1);
        ssrc[pp] = rs[k];
      }
    }
  } else {
    // kc block
    if (t < 32) {
      for (int j = 0; j < 8; ++j) M[t][j] = W1[t * 8 + j];
      float a1 = 0.f, a2 = 0.f;
      for (int j = 0; j < 8; ++j) {
        a1 += Wnb[t * 8 + j] * Watt[j];
        a2 += Wself[t * 8 + j] * Watt[8 + j];
      }
      M[t][8] = a1; M[t][9] = a2;
    }
    __syncthreads();
    if (t < 10) {
      float a = 0.f;
      for (int m = 0; m < 32; ++m) a += b0[m] * M[m][t];
      if (t == 8) { for (int j = 0; j < 8; ++j) a += bnb[j] * Watt[j]; a += batt[0]; }
      if (t == 9) { for (int j = 0; j < 8; ++j) a += bself[j] * Watt[8 + j]; }
      kc[t] = a;
    }
    if (t >= 10 && t < 12) kc[t] = 0.f;
  }
}

// ---------------- agg1: 4 lanes/node (2 dim-halves x 2 edge-strides) ----------------
__global__ __launch_bounds__(256) void k_agg1(const int* __restrict__ off,
                                              const int* __restrict__ ssrc,
                                              const float* __restrict__ y,
                                              const float* __restrict__ kc,
                                              float* __restrict__ hw,
                                              float* __restrict__ s1c,
                                              float* __restrict__ s2c) {
  int tid = blockIdx.x * 256 + threadIdx.x;  // N*4
  if (tid >= N_NODES * 4) return;
  int i = tid >> 2, sub = tid & 3;
  int dh = sub & 1, eh = sub >> 1;
  int p1 = off[i + 1];
  float4 acc = make_float4(0.f, 0.f, 0.f, 0.f);
  float a8 = 0.f, a9 = 0.f;
  for (int p = off[i] + eh; p < p1; p += 2) {
    int r = ssrc[p];
    const float* yr = y + (size_t)r * YD;
    float4 vm, vs = make_float4(0.f, 0.f, 0.f, 0.f);
    float dr;
    if (dh == 0) {
      vs = *(const float4*)(yr + 8);  // {p1, p2, dinv1, dinv1^2}
      dr = vs.z;
      vm = *(const float4*)yr;
    } else {
      vm = *(const float4*)(yr + 4);
      dr = 0.f;
    }
    dr += __shfl_xor(dr, 1);  // pair (dh0,dh1) same edge: both get dinv1[r]
    acc.x += vm.x * dr; acc.y += vm.y * dr; acc.z += vm.z * dr; acc.w += vm.w * dr;
    if (dh == 0) { a8 += vs.x * dr; a9 += vs.y * dr; }
  }
  // combine edge-halves
  acc.x += __shfl_xor(acc.x, 2); acc.y += __shfl_xor(acc.y, 2);
  acc.z += __shfl_xor(acc.z, 2); acc.w += __shfl_xor(acc.w, 2);
  a8 += __shfl_xor(a8, 2); a9 += __shfl_xor(a9, 2);
  if (eh == 0) {
    const float* yi = y + (size_t)i * YD;
    float4 sv, svs = make_float4(0.f, 0.f, 0.f, 0.f);
    float di, di2;
    if (dh == 0) {
      svs = *(const float4*)(yi + 8);
      di = svs.z; di2 = svs.w;
      sv = *(const float4*)yi;
    } else {
      sv = *(const float4*)(yi + 4);
      di = 0.f; di2 = 0.f;
    }
    di += __shfl_xor(di, 1);
    di2 += __shfl_xor(di2, 1);
    if (dh == 0) {
      float4 kq = *(const float4*)kc;
      *(float4*)(hw + (size_t)i * 8) =
          make_float4(di * acc.x + di2 * sv.x + kq.x, di * acc.y + di2 * sv.y + kq.y,
                      di * acc.z + di2 * sv.z + kq.z, di * acc.w + di2 * sv.w + kq.w);
      s1c[i] = di * a8 + di2 * svs.x + kc[8];
      s2c[i] = di * a9 + di2 * svs.y + kc[9];
    } else {
      float4 kq = *(const float4*)(kc + 4);
      *(float4*)(hw + (size_t)i * 8 + 4) =
          make_float4(di * acc.x + di2 * sv.x + kq.x, di * acc.y + di2 * sv.y + kq.y,
                      di * acc.z + di2 * sv.z + kq.z, di * acc.w + di2 * sv.w + kq.w);
    }
  }
}

// ---------------- deg2: 16 lanes/node ----------------
__global__ void k_deg2g(const int* __restrict__ off, const int* __restrict__ ssrc,
                        const float* __restrict__ s1c, const float* __restrict__ s2c,
                        float* __restrict__ dinv2) {
  int tid = blockIdx.x * 256 + threadIdx.x;  // N*16 exactly
  int i = tid >> 4, sub = tid & 15;
  float s2i = s2c[i];
  float sum = 0.f;
  int p1 = off[i + 1];
  for (int p = off[i] + sub; p < p1; p += 16) {
    int r = ssrc[p];
    float w = fmaxf(s1c[r] + s2i, 0.f);
    float m = fminf(1.01f / (1.f + __expf(-w)), 1.f);
    sum += m * w;
  }
#pragma unroll
  for (int d = 1; d < 16; d <<= 1) sum += __shfl_xor(sum, d);
  if (sub == 0) dinv2[i] = rsqrtf(sum + 1.0f);
}

// ---------------- conv2: 4 lanes/node (2 dim-halves x 2 edge-strides) ----------------
__global__ __launch_bounds__(256) void k_conv2g(const int* __restrict__ off,
                                                const int* __restrict__ ssrc,
                                                const float* __restrict__ hw,
                                                const float* __restrict__ s1c,
                                                const float* __restrict__ s2c,
                                                const float* __restrict__ dinv2,
                                                const float* __restrict__ b1,
                                                float* __restrict__ out) {
  int tid = blockIdx.x * 256 + threadIdx.x;  // N*4
  if (tid >= N_NODES * 4) return;
  int i = tid >> 2, sub = tid & 3;
  int q = sub & 1, eh = sub >> 1;
  float s2i = s2c[i];
  float4 acc = make_float4(0.f, 0.f, 0.f, 0.f);
  int p1 = off[i + 1];
  for (int p = off[i] + eh; p < p1; p += 2) {
    int r = ssrc[p];
    float w = fmaxf(s1c[r] + s2i, 0.f);
    float m = fminf(1.01f / (1.f + __expf(-w)), 1.f);
    float cf = m * w * dinv2[r];
    float4 v = *(const float4*)(hw + (size_t)r * 8 + q * 4);
    acc.x += v.x * cf; acc.y += v.y * cf; acc.z += v.z * cf; acc.w += v.w * cf;
  }
  acc.x += __shfl_xor(acc.x, 2); acc.y += __shfl_xor(acc.y, 2);
  acc.z += __shfl_xor(acc.z, 2); acc.w += __shfl_xor(acc.w, 2);
  if (eh == 0) {
    float di = dinv2[i];
    float d2 = di * di;
    float4 sv = *(const float4*)(hw + (size_t)i * 8 + q * 4);
    float4 bq = *(const float4*)(b1 + q * 4);
    *(float4*)(out + (size_t)i * 8 + q * 4) =
        make_float4(di * acc.x + d2 * sv.x + bq.x, di * acc.y + d2 * sv.y + bq.y,
                    di * acc.z + d2 * sv.z + bq.z, di * acc.w + d2 * sv.w + bq.w);
  }
}

extern "C" void kernel_launch(void* const* d_in, const int* in_sizes, int n_in,
                              void* d_out, int out_size, void* d_ws, size_t ws_size,
                              hipStream_t stream) {
  const float* x     = (const float*)d_in[0];
  const int*   eidx  = (const int*)d_in[1];
  const int*   row   = eidx;
  const int*   col   = eidx + N_EDGES;
  const float* W0    = (const float*)d_in[2];
  const float* b0    = (const float*)d_in[3];
  const float* W1    = (const float*)d_in[4];
  const float* b1    = (const float*)d_in[5];
  const float* Wnb   = (const float*)d_in[6];
  const float* bnb   = (const float*)d_in[7];
  const float* Wself = (const float*)d_in[8];
  const float* bself = (const float*)d_in[9];
  const float* Watt  = (const float*)d_in[10];
  const float* batt  = (const float*)d_in[11];
  float* wsf = (float*)d_ws;

  // workspace layout (4-byte units), ~5.0M (~20 MB)
  float* y      = wsf + 0;                     // N*12 (slots 10,11 = dinv1, dinv1^2)
  float* hw     = wsf + 1200000;               // N*8
  int*   ssrc   = (int*)(wsf + 2000000);       // E
  int*   cnt8   = (int*)(wsf + 3600000);       // 8*N (copy0 becomes total)
  int*   off    = (int*)(wsf + 4400000);       // N+1
  int*   cursor = (int*)(wsf + 4500064);       // N
  float* dinv2  = wsf + 4600064;               // N
  float* s1c    = wsf + 4700064;               // N
  float* s2c    = wsf + 4800064;               // N
  int*   bsum   = (int*)(wsf + 4900064);       // 391
  int*   bpre   = (int*)(wsf + 4900512);       // 391
  float* kc     = wsf + 4901056;               // 12

  float* out = (float*)d_out;

  hipMemsetAsync(cnt8, 0, (size_t)8 * N_NODES * sizeof(int), stream);
  k_count<<<CHUNKS, 256, 0, stream>>>(col, cnt8);
  k_scan1<<<SCAN_NB, 256, 0, stream>>>(cnt8, off, bsum);
  k_scan2<<<1, 512, 0, stream>>>(bsum, bpre);
  k_scan3<<<SCAN_NB, 256, 0, stream>>>(cnt8, bpre, off, cursor, y);
  k_phaseE<<<GEMM_NB + SCAT_NB + 1, 256, 0, stream>>>(
      x, W0, W1, Wnb, Wself, Watt, b0, bnb, bself, batt,
      row, col, cursor, ssrc, y, kc);
  k_agg1<<<(N_NODES * 4 + 255) / 256, 256, 0, stream>>>(off, ssrc, y, kc, hw, s1c, s2c);
  k_deg2g<<<N_NODES * 16 / 256, 256, 0, stream>>>(off, ssrc, s1c, s2c, dinv2);
  k_conv2g<<<(N_NODES * 4 + 255) / 256, 256, 0, stream>>>(off, ssrc, hw, s1c, s2c, dinv2, b1, out);
}